// Round 7
// baseline (558.840 us; speedup 1.0000x reference)
//
#include <hip/hip_runtime.h>

#define Nn 32
#define Cc 64
#define Vv 25
#define Tt 1024

typedef __attribute__((ext_vector_type(4))) float f32x4;
typedef __attribute__((ext_vector_type(8))) short bf16x8;
typedef __attribute__((ext_vector_type(4))) unsigned short u16x4;

__device__ __forceinline__ unsigned short f2bf(float f) {
    union { float f; unsigned u; } a; a.f = f;
    unsigned u = a.u;
    u += 0x7fff + ((u >> 16) & 1);   // RNE
    return (unsigned short)(u >> 16);
}

// ---------------- fast path ----------------

// Fused prep (R5, near traffic floor): blocks [0,625) build Weff (swizzled);
// blocks [625,7025) convert x -> xb, 64c' x 128t tile, LDS-free, both sides
// 128B-coalesced.
__global__ __launch_bounds__(256) void prep_fused(
        const float* __restrict__ x, const float* __restrict__ W,
        const float* __restrict__ A, unsigned short* __restrict__ xb,
        unsigned short* __restrict__ Weff) {
    int bid = blockIdx.x;
    if (bid < Vv * Vv) {
        // ---- Weff part ----
        int v = bid / Vv;
        int w = bid - v * Vv;
        float a0 = A[(0 * Vv + w) * Vv + v];
        float a1 = A[(1 * Vv + w) * Vv + v];
        float a2 = A[(2 * Vv + w) * Vv + v];
        const float* Wb = W + (size_t)w * 192 * 64;
        unsigned short* o = Weff + (size_t)(v * Vv + w) * 4096;
        int c  = threadIdx.x >> 2;
        int c0 = (threadIdx.x & 3) * 16;
        #pragma unroll
        for (int i = 0; i < 16; ++i) {
            int cp = c0 + i;
            float val = a0 * Wb[(c * 3 + 0) * 64 + cp]
                      + a1 * Wb[(c * 3 + 1) * 64 + cp]
                      + a2 * Wb[(c * 3 + 2) * 64 + cp];
            int jl = cp >> 3;
            o[c * 64 + ((jl ^ (c & 7)) << 3) + (cp & 7)] = f2bf(val);
        }
        return;
    }
    // ---- x-convert part: tile = (n, w, 128t), no LDS ----
    int pid = bid - Vv * Vv;
    int n = pid / (Vv * 8);
    int rem = pid - n * (Vv * 8);
    int w = rem >> 3;
    int t0 = (rem & 7) << 7;      // 128-t slice

    int tid = threadIdx.x;
    int wv = tid >> 6;            // wave covers t-window [t0+wv*32, +32)
    int l  = tid & 63;
    int jl = l & 7;               // c'-octet 0..7
    int tg = l >> 3;              // t-quad 0..7

    int tbase = t0 + wv * 32 + tg * 4;
    const float* xn = x + ((size_t)(n * Cc) * Vv + w) * Tt + tbase;
    unsigned short* dst = xb + ((size_t)(n * Vv + w) * Tt) * 64;

    f32x4 f[8];
    #pragma unroll
    for (int k = 0; k < 8; ++k) {
        int r = jl * 8 + k;
        f[k] = __builtin_nontemporal_load(
            (const f32x4*)(xn + (size_t)r * (Vv * Tt)));
    }
    #pragma unroll
    for (int j = 0; j < 4; ++j) {
        bf16x8 o;
        #pragma unroll
        for (int k = 0; k < 8; ++k) o[k] = (short)f2bf(f[k][j]);
        int tl = tbase + j;
        int pc = jl ^ (tl & 7);
        *(bf16x8*)&dst[(size_t)tl * 64 + pc * 8] = o;   // 128B/row per wave
    }
}

// out[n, 0:64, v, t0:t0+256] = sum_w Weff[v,w] @ xb[n,w,t0:t0+256,:]
// BARRIER-FREE: no LDS, no s_barrier. Both A (Weff, L2-hot, ~200KB/v) and B
// (xb slice, L2-hot per XCD) fragments loaded direct global->reg. Waves
// free-run, so one wave's vmcnt stall overlaps the other SIMD-resident
// wave's MFMA burst (the per-step s_barrier in R3-R6 forced lockstep and
// capped MfmaUtil at ~35%). Distance-2, compute-then-issue, 2 buffer pairs:
//   step w: vmcnt(16) [= one younger step's 16 loads] -> COMPUTE(pair(w))
//           -> ISSUE(pair(w) <- w+2)
// sched_barrier(0) fences pin the blocks (R1's failure was the scheduler
// sinking the prefetch). Registers: 4x32 operand + 64 acc ~ 210 total ->
// 2 waves/SIMD, no spill (watch WRITE_SIZE ~205MB; jump = spill, revert).
__global__ __launch_bounds__(256, 2) void gc_fast(
        const unsigned short* __restrict__ xb,
        const unsigned short* __restrict__ Weff,
        float* __restrict__ out) {
    int bid = blockIdx.x;                 // 3200 = 8 xcd * (16 slices * 25 v), v fastest
    int xcd = bid & 7;
    int lid = bid >> 3;
    int v = lid % Vv;
    int s = lid / Vv;                     // 0..15
    int slice = (xcd << 4) + s;           // 0..127
    int n  = slice >> 2;
    int t0 = (slice & 3) << 8;

    int tid = threadIdx.x;
    int lane = tid & 63, wv = tid >> 6;
    int m = lane & 15, quad = lane >> 4;

    const unsigned short* wg = Weff + (size_t)v * (Vv * 4096);
    const unsigned short* xbase = xb + ((size_t)(n * Vv) * Tt + t0) * 64;

    int coff0 = ((quad)     ^ (m & 7)) << 3;   // kc=0 chunk offset (swizzled)
    int coff1 = ((4 + quad) ^ (m & 7)) << 3;   // kc=1
    int trow[4], arow[4];
    #pragma unroll
    for (int ni = 0; ni < 4; ++ni) trow[ni] = (wv * 64 + ni * 16 + m) * 64;
    #pragma unroll
    for (int mi = 0; mi < 4; ++mi) arow[mi] = (mi * 16 + m) * 64;

    f32x4 acc[4][4];
    #pragma unroll
    for (int i = 0; i < 4; ++i)
        #pragma unroll
        for (int j = 0; j < 4; ++j)
            acc[i][j] = (f32x4){0.f, 0.f, 0.f, 0.f};

    bf16x8 aA[8], bA[8], aB[8], bB[8];

#define ISSUE(AR, BR, w_) do { \
    const unsigned short* aw_ = wg + (size_t)(w_) * 4096; \
    const unsigned short* xw_ = xbase + (size_t)(w_) * (Tt * 64); \
    _Pragma("unroll") \
    for (int mi_ = 0; mi_ < 4; ++mi_) { \
        AR[mi_]     = *(const bf16x8*)(aw_ + arow[mi_] + coff0); \
        AR[mi_ + 4] = *(const bf16x8*)(aw_ + arow[mi_] + coff1); \
    } \
    _Pragma("unroll") \
    for (int ni_ = 0; ni_ < 4; ++ni_) { \
        BR[ni_]     = *(const bf16x8*)(xw_ + trow[ni_] + coff0); \
        BR[ni_ + 4] = *(const bf16x8*)(xw_ + trow[ni_] + coff1); \
    } \
} while (0)

#define COMPUTE(AC, BC) do { \
    __builtin_amdgcn_s_setprio(1); \
    _Pragma("unroll") \
    for (int mi_ = 0; mi_ < 4; ++mi_) \
        _Pragma("unroll") \
        for (int ni_ = 0; ni_ < 4; ++ni_) \
            acc[mi_][ni_] = __builtin_amdgcn_mfma_f32_16x16x32_bf16( \
                AC[mi_], BC[ni_], acc[mi_][ni_], 0, 0, 0); \
    _Pragma("unroll") \
    for (int mi_ = 0; mi_ < 4; ++mi_) \
        _Pragma("unroll") \
        for (int ni_ = 0; ni_ < 4; ++ni_) \
            acc[mi_][ni_] = __builtin_amdgcn_mfma_f32_16x16x32_bf16( \
                AC[mi_ + 4], BC[ni_ + 4], acc[mi_][ni_], 0, 0, 0); \
    __builtin_amdgcn_s_setprio(0); \
} while (0)

#define STEP(AC, BC, w_) do { \
    asm volatile("s_waitcnt vmcnt(16)" ::: "memory"); \
    __builtin_amdgcn_sched_barrier(0); \
    COMPUTE(AC, BC); \
    __builtin_amdgcn_sched_barrier(0); \
    ISSUE(AC, BC, (w_) + 2); \
    __builtin_amdgcn_sched_barrier(0); \
} while (0)

    // prologue: w=0 -> pair A, w=1 -> pair B
    ISSUE(aA, bA, 0);
    ISSUE(aB, bB, 1);
    __builtin_amdgcn_sched_barrier(0);

    // w = 0..22: even -> pair A, odd -> pair B; each step re-issues w+2 into
    // the pair it just consumed.
    STEP(aA, bA,  0);
    STEP(aB, bB,  1);
    STEP(aA, bA,  2);
    STEP(aB, bB,  3);
    STEP(aA, bA,  4);
    STEP(aB, bB,  5);
    STEP(aA, bA,  6);
    STEP(aB, bB,  7);
    STEP(aA, bA,  8);
    STEP(aB, bB,  9);
    STEP(aA, bA, 10);
    STEP(aB, bB, 11);
    STEP(aA, bA, 12);
    STEP(aB, bB, 13);
    STEP(aA, bA, 14);
    STEP(aB, bB, 15);
    STEP(aA, bA, 16);
    STEP(aB, bB, 17);
    STEP(aA, bA, 18);
    STEP(aB, bB, 19);
    STEP(aA, bA, 20);
    STEP(aB, bB, 21);
    STEP(aA, bA, 22);
    // tail w=23: only w=24's 16 loads outstanding
    asm volatile("s_waitcnt vmcnt(16)" ::: "memory");
    __builtin_amdgcn_sched_barrier(0);
    COMPUTE(aB, bB);
    // tail w=24
    asm volatile("s_waitcnt vmcnt(0)" ::: "memory");
    __builtin_amdgcn_sched_barrier(0);
    COMPUTE(aA, bA);

#undef ISSUE
#undef COMPUTE
#undef STEP

    // epilogue: D layout col(t)=lane&15, row(c)=quad*4+reg  (verified in R1)
    // nontemporal: out is write-once, keep xb resident in L2.
    float* og = out + ((size_t)n * Cc * Vv + v) * Tt + t0 + wv * 64 + m;
    #pragma unroll
    for (int mi = 0; mi < 4; ++mi)
        #pragma unroll
        for (int r = 0; r < 4; ++r) {
            int c = mi * 16 + quad * 4 + r;
            float* orow = og + (size_t)c * Vv * Tt;
            #pragma unroll
            for (int ni = 0; ni < 4; ++ni)
                __builtin_nontemporal_store(acc[mi][ni][r], &orow[ni * 16]);
        }
}

// ---------------- fallback path (R1, proven) ----------------

__global__ __launch_bounds__(256) void weff_prep_plain(
        const float* __restrict__ W, const float* __restrict__ A,
        unsigned short* __restrict__ Weff) {
    int v = blockIdx.x / Vv;
    int w = blockIdx.x - v * Vv;
    float a0 = A[(0 * Vv + w) * Vv + v];
    float a1 = A[(1 * Vv + w) * Vv + v];
    float a2 = A[(2 * Vv + w) * Vv + v];
    const float* Wb = W + (size_t)w * 192 * 64;
    unsigned short* o = Weff + (size_t)(v * Vv + w) * 4096;
    int e0 = threadIdx.x * 16;
    #pragma unroll
    for (int i = 0; i < 16; ++i) {
        int e = e0 + i;
        int c = e >> 6, cp = e & 63;
        float val = a0 * Wb[(c * 3 + 0) * 64 + cp]
                  + a1 * Wb[(c * 3 + 1) * 64 + cp]
                  + a2 * Wb[(c * 3 + 2) * 64 + cp];
        o[e] = f2bf(val);
    }
}

__global__ __launch_bounds__(256, 2) void gc_plain(
        const float* __restrict__ x, const unsigned short* __restrict__ Weff,
        float* __restrict__ out) {
    __shared__ __align__(16) unsigned short xs[256 * 72];
    __shared__ __align__(16) unsigned short wa[64 * 72];
    int bid = blockIdx.x;
    int xcd = bid & 7;
    int lid = bid >> 3;
    int v, s;
    if (lid < 13 * 16) { v = lid % 13;            s = lid / 13; }
    else { int l2 = lid - 13 * 16; v = 13 + l2 % 12; s = l2 / 12; }
    int slice = (xcd << 4) + s;
    int n  = slice >> 2;
    int t0 = (slice & 3) << 8;
    int tid  = threadIdx.x;
    int lane = tid & 63;
    int wv   = tid >> 6;
    int m    = lane & 15;
    int quad = lane >> 4;
    int cc = tid & 7;
    int tt = tid >> 3;
    f32x4 acc[4][4];
    #pragma unroll
    for (int i = 0; i < 4; ++i)
        #pragma unroll
        for (int j = 0; j < 4; ++j)
            acc[i][j] = (f32x4){0.f, 0.f, 0.f, 0.f};
    const float* xg = x + (size_t)n * Cc * Vv * Tt + t0 + tt * 4;
    const bf16x8* wg = (const bf16x8*)(Weff + (size_t)v * Vv * 4096);
    for (int w = 0; w < Vv; ++w) {
        if (w) __syncthreads();
        #pragma unroll
        for (int r = 0; r < 2; ++r) {
            int q = r * 256 + tid;
            int c = q >> 3, b = q & 7;
            *(bf16x8*)&wa[c * 72 + b * 8] = wg[w * 512 + q];
        }
        {
            bf16x8 rows[8];
            #pragma unroll
            for (int i = 0; i < 8; ++i) {
                int cp = cc * 8 + i;
                const float* p = xg + ((size_t)cp * Vv + w) * Tt;
                float4 f0 = *(const float4*)p;
                float4 f1 = *(const float4*)(p + 128);
                rows[0][i] = (short)f2bf(f0.x); rows[1][i] = (short)f2bf(f0.y);
                rows[2][i] = (short)f2bf(f0.z); rows[3][i] = (short)f2bf(f0.w);
                rows[4][i] = (short)f2bf(f1.x); rows[5][i] = (short)f2bf(f1.y);
                rows[6][i] = (short)f2bf(f1.z); rows[7][i] = (short)f2bf(f1.w);
            }
            #pragma unroll
            for (int j = 0; j < 4; ++j) {
                *(bf16x8*)&xs[(tt * 4 + j) * 72 + cc * 8]       = rows[j];
                *(bf16x8*)&xs[(128 + tt * 4 + j) * 72 + cc * 8] = rows[4 + j];
            }
        }
        __syncthreads();
        #pragma unroll
        for (int kc = 0; kc < 2; ++kc) {
            int ko = kc * 32 + quad * 8;
            bf16x8 afr[4], bfr[4];
            #pragma unroll
            for (int mi = 0; mi < 4; ++mi)
                afr[mi] = *(const bf16x8*)&wa[(mi * 16 + m) * 72 + ko];
            #pragma unroll
            for (int ni = 0; ni < 4; ++ni)
                bfr[ni] = *(const bf16x8*)&xs[(wv * 64 + ni * 16 + m) * 72 + ko];
            #pragma unroll
            for (int mi = 0; mi < 4; ++mi)
                #pragma unroll
                for (int ni = 0; ni < 4; ++ni)
                    acc[mi][ni] = __builtin_amdgcn_mfma_f32_16x16x32_bf16(
                        afr[mi], bfr[ni], acc[mi][ni], 0, 0, 0);
        }
    }
    float* og = out + ((size_t)n * Cc * Vv + v) * Tt + t0 + wv * 64 + m;
    #pragma unroll
    for (int mi = 0; mi < 4; ++mi)
        #pragma unroll
        for (int r = 0; r < 4; ++r) {
            int c = mi * 16 + quad * 4 + r;
            float* orow = og + (size_t)c * Vv * Tt;
            #pragma unroll
            for (int ni = 0; ni < 4; ++ni)
                orow[ni * 16] = acc[mi][ni][r];
        }
}

extern "C" void kernel_launch(void* const* d_in, const int* in_sizes, int n_in,
                              void* d_out, int out_size, void* d_ws, size_t ws_size,
                              hipStream_t stream) {
    const float* x = (const float*)d_in[0];   // [32,64,25,1024]
    const float* W = (const float*)d_in[1];   // [25,192,64]
    const float* A = (const float*)d_in[2];   // [3,25,25]
    float* out = (float*)d_out;

    const size_t xb_elems   = (size_t)Nn * Vv * Tt * 64;       // 52,428,800
    const size_t weff_elems = (size_t)Vv * Vv * 4096;          //  2,560,000
    const size_t need = (xb_elems + weff_elems) * sizeof(unsigned short);

    if (ws_size >= need) {
        unsigned short* xb   = (unsigned short*)d_ws;
        unsigned short* Weff = xb + xb_elems;
        prep_fused<<<dim3(Vv * Vv + Nn * Vv * 8), dim3(256), 0, stream>>>(x, W, A, xb, Weff);
        gc_fast<<<dim3(3200), dim3(256), 0, stream>>>(xb, Weff, out);
    } else {
        unsigned short* Weff = (unsigned short*)d_ws;
        weff_prep_plain<<<dim3(Vv * Vv), dim3(256), 0, stream>>>(W, A, Weff);
        gc_plain<<<dim3(3200), dim3(256), 0, stream>>>(x, Weff, out);
    }
}

// Round 8
// 501.477 us; speedup vs baseline: 1.1144x; 1.1144x over previous
//
#include <hip/hip_runtime.h>

#define Nn 32
#define Cc 64
#define Vv 25
#define Tt 1024

typedef __attribute__((ext_vector_type(4))) float f32x4;
typedef __attribute__((ext_vector_type(8))) short bf16x8;
typedef __attribute__((ext_vector_type(4))) unsigned short u16x4;

__device__ __forceinline__ unsigned short f2bf(float f) {
    union { float f; unsigned u; } a; a.f = f;
    unsigned u = a.u;
    u += 0x7fff + ((u >> 16) & 1);   // RNE
    return (unsigned short)(u >> 16);
}

__device__ __forceinline__ void gl_lds16(const unsigned short* g, unsigned short* l) {
    __builtin_amdgcn_global_load_lds(
        (const __attribute__((address_space(1))) unsigned int*)g,
        (__attribute__((address_space(3))) unsigned int*)l, 16, 0, 0);
}

// ---------------- fast path ----------------

// Fused prep (R5, near traffic floor): blocks [0,625) build Weff (swizzled);
// blocks [625,7025) convert x -> xb, 64c' x 128t tile, LDS-free, both sides
// 128B-coalesced.
__global__ __launch_bounds__(256) void prep_fused(
        const float* __restrict__ x, const float* __restrict__ W,
        const float* __restrict__ A, unsigned short* __restrict__ xb,
        unsigned short* __restrict__ Weff) {
    int bid = blockIdx.x;
    if (bid < Vv * Vv) {
        // ---- Weff part ----
        int v = bid / Vv;
        int w = bid - v * Vv;
        float a0 = A[(0 * Vv + w) * Vv + v];
        float a1 = A[(1 * Vv + w) * Vv + v];
        float a2 = A[(2 * Vv + w) * Vv + v];
        const float* Wb = W + (size_t)w * 192 * 64;
        unsigned short* o = Weff + (size_t)(v * Vv + w) * 4096;
        int c  = threadIdx.x >> 2;
        int c0 = (threadIdx.x & 3) * 16;
        #pragma unroll
        for (int i = 0; i < 16; ++i) {
            int cp = c0 + i;
            float val = a0 * Wb[(c * 3 + 0) * 64 + cp]
                      + a1 * Wb[(c * 3 + 1) * 64 + cp]
                      + a2 * Wb[(c * 3 + 2) * 64 + cp];
            int jl = cp >> 3;
            o[c * 64 + ((jl ^ (c & 7)) << 3) + (cp & 7)] = f2bf(val);
        }
        return;
    }
    // ---- x-convert part: tile = (n, w, 128t), no LDS ----
    int pid = bid - Vv * Vv;
    int n = pid / (Vv * 8);
    int rem = pid - n * (Vv * 8);
    int w = rem >> 3;
    int t0 = (rem & 7) << 7;      // 128-t slice

    int tid = threadIdx.x;
    int wv = tid >> 6;            // wave covers t-window [t0+wv*32, +32)
    int l  = tid & 63;
    int jl = l & 7;               // c'-octet 0..7
    int tg = l >> 3;              // t-quad 0..7

    int tbase = t0 + wv * 32 + tg * 4;
    const float* xn = x + ((size_t)(n * Cc) * Vv + w) * Tt + tbase;
    unsigned short* dst = xb + ((size_t)(n * Vv + w) * Tt) * 64;

    f32x4 f[8];
    #pragma unroll
    for (int k = 0; k < 8; ++k) {
        int r = jl * 8 + k;
        f[k] = __builtin_nontemporal_load(
            (const f32x4*)(xn + (size_t)r * (Vv * Tt)));
    }
    #pragma unroll
    for (int j = 0; j < 4; ++j) {
        bf16x8 o;
        #pragma unroll
        for (int k = 0; k < 8; ++k) o[k] = (short)f2bf(f[k][j]);
        int tl = tbase + j;
        int pc = jl ^ (tl & 7);
        *(bf16x8*)&dst[(size_t)tl * 64 + pc * 8] = o;   // 128B/row per wave
    }
}

// out[n, 0:64, v, t0:t0+256] = sum_w Weff[v,w] @ xb[n,w,t0:t0+256,:]
// DOUBLE-STEP lockstep pipeline (R5 mechanics, half the barriers):
//   - A: global_load_lds into RING-8 LDS (64KB). Buf written at step p was
//     last read at step p-2; barrier(p-1) separates -> race-free.
//   - B: 3 reg buffers (96 VGPR, the budget proven to survive regalloc in
//     R3/R5; 4 buffers collapse - R7). Per w, buffer w%3. Mid-step issue
//     refills the buffer freed by the first compute.
//   - One s_barrier per DOUBLE step: 13 total (was 25).
// Step p (w=2p,2p+1):  [vmcnt ledger in brackets = allowed-outstanding]
//   .1 ISSUE_B(w+2)            (8 vm)
//   .2 ISSUE_A(w+4), A(w+5)    (4 vm)
//   .3 vmcnt(24) [= p.2(4)+p.1(8)+(p-1).5(8)+(p-1).2(4)]; s_barrier
//   .4 COMPUTE(w)
//   .5 ISSUE_B(w+3)            (8 vm)
//   .6 vmcnt(20) [= p.5(8)+p.2(4)+p.1(8)]; COMPUTE(w+1)
// Specials: p0 .3=16 (prologue queue), p10 .3=22/.6=18 (A(24) is 2 ops),
// p11 .3=18/.6=10, tail vmcnt(0)+barrier.
__global__ __launch_bounds__(256, 2) void gc_fast(
        const unsigned short* __restrict__ xb,
        const unsigned short* __restrict__ Weff,
        float* __restrict__ out) {
    __shared__ __align__(16) unsigned short wa[8][4096];   // 64 KB ring-8

    int bid = blockIdx.x;                 // 3200 = 8 xcd * (16 slices * 25 v), v fastest
    int xcd = bid & 7;
    int lid = bid >> 3;
    int v = lid % Vv;
    int s = lid / Vv;                     // 0..15
    int slice = (xcd << 4) + s;           // 0..127
    int n  = slice >> 2;
    int t0 = (slice & 3) << 8;

    int tid = threadIdx.x;
    int lane = tid & 63, wv = tid >> 6;
    int m = lane & 15, quad = lane >> 4;

    const unsigned short* wg = Weff + (size_t)v * (Vv * 4096);
    const unsigned short* xbase = xb + ((size_t)(n * Vv) * Tt + t0) * 64;

    int coff0 = ((quad)     ^ (m & 7)) << 3;   // kc=0 chunk offset (swizzled)
    int coff1 = ((4 + quad) ^ (m & 7)) << 3;   // kc=1
    int trow[4], arow[4];
    #pragma unroll
    for (int ni = 0; ni < 4; ++ni) trow[ni] = (wv * 64 + ni * 16 + m) * 64;
    #pragma unroll
    for (int mi = 0; mi < 4; ++mi) arow[mi] = (mi * 16 + m) * 64;

    f32x4 acc[4][4];
    #pragma unroll
    for (int i = 0; i < 4; ++i)
        #pragma unroll
        for (int j = 0; j < 4; ++j)
            acc[i][j] = (f32x4){0.f, 0.f, 0.f, 0.f};

    bf16x8 b0v[8], b1v[8], b2v[8];

#define SB __builtin_amdgcn_sched_barrier(0)
#define VMCNT(N_) asm volatile("s_waitcnt vmcnt(" #N_ ")" ::: "memory")

#define ISSUE_A(WBUF, w_) do { \
    const unsigned short* s_ = wg + (size_t)(w_) * 4096 + tid * 8; \
    gl_lds16(s_,        &wa[WBUF][tid * 8]); \
    gl_lds16(s_ + 2048, &wa[WBUF][2048 + tid * 8]); \
} while (0)

#define ISSUE_B(BN, w_) do { \
    const unsigned short* xw_ = xbase + (size_t)(w_) * (Tt * 64); \
    _Pragma("unroll") \
    for (int ni_ = 0; ni_ < 4; ++ni_) { \
        BN[ni_]     = *(const bf16x8*)(xw_ + trow[ni_] + coff0); \
        BN[ni_ + 4] = *(const bf16x8*)(xw_ + trow[ni_] + coff1); \
    } \
} while (0)

#define COMP(RBUF, BC) do { \
    const unsigned short* cur_ = &wa[RBUF][0]; \
    bf16x8 af_[8]; \
    _Pragma("unroll") \
    for (int mi_ = 0; mi_ < 4; ++mi_) { \
        af_[mi_]     = *(const bf16x8*)(cur_ + arow[mi_] + coff0); \
        af_[mi_ + 4] = *(const bf16x8*)(cur_ + arow[mi_] + coff1); \
    } \
    __builtin_amdgcn_s_setprio(1); \
    _Pragma("unroll") \
    for (int mi_ = 0; mi_ < 4; ++mi_) \
        _Pragma("unroll") \
        for (int ni_ = 0; ni_ < 4; ++ni_) \
            acc[mi_][ni_] = __builtin_amdgcn_mfma_f32_16x16x32_bf16( \
                af_[mi_], BC[ni_], acc[mi_][ni_], 0, 0, 0); \
    _Pragma("unroll") \
    for (int mi_ = 0; mi_ < 4; ++mi_) \
        _Pragma("unroll") \
        for (int ni_ = 0; ni_ < 4; ++ni_) \
            acc[mi_][ni_] = __builtin_amdgcn_mfma_f32_16x16x32_bf16( \
                af_[mi_ + 4], BC[ni_ + 4], acc[mi_][ni_], 0, 0, 0); \
    __builtin_amdgcn_s_setprio(0); \
} while (0)

// Double-step: R0/R1 = LDS bufs read (w, w+1); W4/W5 = bufs written (w+4,w+5);
// C0/C1 = B bufs consumed; I2/I3 = B bufs filled (w+2, w+3). N3/N6 = vmcnt.
#define DSTEP(R0, R1, W4, W5, C0, C1, I2, I3, w_, N3, N6) do { \
    ISSUE_B(I2, (w_) + 2); \
    ISSUE_A(W4, (w_) + 4); \
    ISSUE_A(W5, (w_) + 5); \
    SB; VMCNT(N3); SB; \
    __builtin_amdgcn_s_barrier(); \
    SB; \
    COMP(R0, C0); \
    SB; \
    ISSUE_B(I3, (w_) + 3); \
    SB; VMCNT(N6); SB; \
    COMP(R1, C1); \
    SB; \
} while (0)

    // prologue: B(0)->b0, B(1)->b1 (16 vm); A(0..3)->bufs0..3 (8 vm)
    ISSUE_B(b0v, 0);
    ISSUE_B(b1v, 1);
    ISSUE_A(0, 0);
    ISSUE_A(1, 1);
    ISSUE_A(2, 2);
    ISSUE_A(3, 3);
    SB;

    //     R0 R1 W4 W5  C0   C1   I2   I3   w   N3  N6
    DSTEP(0, 1, 4, 5, b0v, b1v, b2v, b0v,  0, 16, 20);   // p0 (prologue queue)
    DSTEP(2, 3, 6, 7, b2v, b0v, b1v, b2v,  2, 24, 20);   // p1
    DSTEP(4, 5, 0, 1, b1v, b2v, b0v, b1v,  4, 24, 20);   // p2
    DSTEP(6, 7, 2, 3, b0v, b1v, b2v, b0v,  6, 24, 20);   // p3
    DSTEP(0, 1, 4, 5, b2v, b0v, b1v, b2v,  8, 24, 20);   // p4
    DSTEP(2, 3, 6, 7, b1v, b2v, b0v, b1v, 10, 24, 20);   // p5
    DSTEP(4, 5, 0, 1, b0v, b1v, b2v, b0v, 12, 24, 20);   // p6
    DSTEP(6, 7, 2, 3, b2v, b0v, b1v, b2v, 14, 24, 20);   // p7
    DSTEP(0, 1, 4, 5, b1v, b2v, b0v, b1v, 16, 24, 20);   // p8
    DSTEP(2, 3, 6, 7, b0v, b1v, b2v, b0v, 18, 24, 20);   // p9

    // p10: w=20,21. Issues B(22)->b1, A(24)->buf0 (2 vm only), B(23)->b2.
    ISSUE_B(b1v, 22);
    ISSUE_A(0, 24);
    SB; VMCNT(22); SB;
    __builtin_amdgcn_s_barrier();
    SB;
    COMP(4, b2v);
    SB;
    ISSUE_B(b2v, 23);
    SB; VMCNT(18); SB;
    COMP(5, b0v);
    SB;

    // p11: w=22,23. Issues B(24)->b0 only.
    ISSUE_B(b0v, 24);
    SB; VMCNT(18); SB;
    __builtin_amdgcn_s_barrier();
    SB;
    COMP(6, b1v);
    SB; VMCNT(10); SB;
    COMP(7, b2v);
    SB;

    // tail w=24: drain everything (A(24) DMA + B(24)), barrier, compute.
    VMCNT(0);
    SB;
    __builtin_amdgcn_s_barrier();
    SB;
    COMP(0, b0v);

#undef DSTEP
#undef COMP
#undef ISSUE_B
#undef ISSUE_A
#undef VMCNT
#undef SB

    // epilogue: D layout col(t)=lane&15, row(c)=quad*4+reg  (verified in R1)
    // nontemporal: out is write-once, keep xb resident in L2.
    float* og = out + ((size_t)n * Cc * Vv + v) * Tt + t0 + wv * 64 + m;
    #pragma unroll
    for (int mi = 0; mi < 4; ++mi)
        #pragma unroll
        for (int r = 0; r < 4; ++r) {
            int c = mi * 16 + quad * 4 + r;
            float* orow = og + (size_t)c * Vv * Tt;
            #pragma unroll
            for (int ni = 0; ni < 4; ++ni)
                __builtin_nontemporal_store(acc[mi][ni][r], &orow[ni * 16]);
        }
}

// ---------------- fallback path (R1, proven) ----------------

__global__ __launch_bounds__(256) void weff_prep_plain(
        const float* __restrict__ W, const float* __restrict__ A,
        unsigned short* __restrict__ Weff) {
    int v = blockIdx.x / Vv;
    int w = blockIdx.x - v * Vv;
    float a0 = A[(0 * Vv + w) * Vv + v];
    float a1 = A[(1 * Vv + w) * Vv + v];
    float a2 = A[(2 * Vv + w) * Vv + v];
    const float* Wb = W + (size_t)w * 192 * 64;
    unsigned short* o = Weff + (size_t)(v * Vv + w) * 4096;
    int e0 = threadIdx.x * 16;
    #pragma unroll
    for (int i = 0; i < 16; ++i) {
        int e = e0 + i;
        int c = e >> 6, cp = e & 63;
        float val = a0 * Wb[(c * 3 + 0) * 64 + cp]
                  + a1 * Wb[(c * 3 + 1) * 64 + cp]
                  + a2 * Wb[(c * 3 + 2) * 64 + cp];
        o[e] = f2bf(val);
    }
}

__global__ __launch_bounds__(256, 2) void gc_plain(
        const float* __restrict__ x, const unsigned short* __restrict__ Weff,
        float* __restrict__ out) {
    __shared__ __align__(16) unsigned short xs[256 * 72];
    __shared__ __align__(16) unsigned short wa[64 * 72];
    int bid = blockIdx.x;
    int xcd = bid & 7;
    int lid = bid >> 3;
    int v, s;
    if (lid < 13 * 16) { v = lid % 13;            s = lid / 13; }
    else { int l2 = lid - 13 * 16; v = 13 + l2 % 12; s = l2 / 12; }
    int slice = (xcd << 4) + s;
    int n  = slice >> 2;
    int t0 = (slice & 3) << 8;
    int tid  = threadIdx.x;
    int lane = tid & 63;
    int wv   = tid >> 6;
    int m    = lane & 15;
    int quad = lane >> 4;
    int cc = tid & 7;
    int tt = tid >> 3;
    f32x4 acc[4][4];
    #pragma unroll
    for (int i = 0; i < 4; ++i)
        #pragma unroll
        for (int j = 0; j < 4; ++j)
            acc[i][j] = (f32x4){0.f, 0.f, 0.f, 0.f};
    const float* xg = x + (size_t)n * Cc * Vv * Tt + t0 + tt * 4;
    const bf16x8* wg = (const bf16x8*)(Weff + (size_t)v * Vv * 4096);
    for (int w = 0; w < Vv; ++w) {
        if (w) __syncthreads();
        #pragma unroll
        for (int r = 0; r < 2; ++r) {
            int q = r * 256 + tid;
            int c = q >> 3, b = q & 7;
            *(bf16x8*)&wa[c * 72 + b * 8] = wg[w * 512 + q];
        }
        {
            bf16x8 rows[8];
            #pragma unroll
            for (int i = 0; i < 8; ++i) {
                int cp = cc * 8 + i;
                const float* p = xg + ((size_t)cp * Vv + w) * Tt;
                float4 f0 = *(const float4*)p;
                float4 f1 = *(const float4*)(p + 128);
                rows[0][i] = (short)f2bf(f0.x); rows[1][i] = (short)f2bf(f0.y);
                rows[2][i] = (short)f2bf(f0.z); rows[3][i] = (short)f2bf(f0.w);
                rows[4][i] = (short)f2bf(f1.x); rows[5][i] = (short)f2bf(f1.y);
                rows[6][i] = (short)f2bf(f1.z); rows[7][i] = (short)f2bf(f1.w);
            }
            #pragma unroll
            for (int j = 0; j < 4; ++j) {
                *(bf16x8*)&xs[(tt * 4 + j) * 72 + cc * 8]       = rows[j];
                *(bf16x8*)&xs[(128 + tt * 4 + j) * 72 + cc * 8] = rows[4 + j];
            }
        }
        __syncthreads();
        #pragma unroll
        for (int kc = 0; kc < 2; ++kc) {
            int ko = kc * 32 + quad * 8;
            bf16x8 afr[4], bfr[4];
            #pragma unroll
            for (int mi = 0; mi < 4; ++mi)
                afr[mi] = *(const bf16x8*)&wa[(mi * 16 + m) * 72 + ko];
            #pragma unroll
            for (int ni = 0; ni < 4; ++ni)
                bfr[ni] = *(const bf16x8*)&xs[(wv * 64 + ni * 16 + m) * 72 + ko];
            #pragma unroll
            for (int mi = 0; mi < 4; ++mi)
                #pragma unroll
                for (int ni = 0; ni < 4; ++ni)
                    acc[mi][ni] = __builtin_amdgcn_mfma_f32_16x16x32_bf16(
                        afr[mi], bfr[ni], acc[mi][ni], 0, 0, 0);
        }
    }
    float* og = out + ((size_t)n * Cc * Vv + v) * Tt + t0 + wv * 64 + m;
    #pragma unroll
    for (int mi = 0; mi < 4; ++mi)
        #pragma unroll
        for (int r = 0; r < 4; ++r) {
            int c = mi * 16 + quad * 4 + r;
            float* orow = og + (size_t)c * Vv * Tt;
            #pragma unroll
            for (int ni = 0; ni < 4; ++ni)
                orow[ni * 16] = acc[mi][ni][r];
        }
}

extern "C" void kernel_launch(void* const* d_in, const int* in_sizes, int n_in,
                              void* d_out, int out_size, void* d_ws, size_t ws_size,
                              hipStream_t stream) {
    const float* x = (const float*)d_in[0];   // [32,64,25,1024]
    const float* W = (const float*)d_in[1];   // [25,192,64]
    const float* A = (const float*)d_in[2];   // [3,25,25]
    float* out = (float*)d_out;

    const size_t xb_elems   = (size_t)Nn * Vv * Tt * 64;       // 52,428,800
    const size_t weff_elems = (size_t)Vv * Vv * 4096;          //  2,560,000
    const size_t need = (xb_elems + weff_elems) * sizeof(unsigned short);

    if (ws_size >= need) {
        unsigned short* xb   = (unsigned short*)d_ws;
        unsigned short* Weff = xb + xb_elems;
        prep_fused<<<dim3(Vv * Vv + Nn * Vv * 8), dim3(256), 0, stream>>>(x, W, A, xb, Weff);
        gc_fast<<<dim3(3200), dim3(256), 0, stream>>>(xb, Weff, out);
    } else {
        unsigned short* Weff = (unsigned short*)d_ws;
        weff_prep_plain<<<dim3(Vv * Vv), dim3(256), 0, stream>>>(W, A, Weff);
        gc_plain<<<dim3(3200), dim3(256), 0, stream>>>(x, Weff, out);
    }
}